// Round 11
// baseline (344.519 us; speedup 1.0000x reference)
//
#include <hip/hip_runtime.h>
#include <hip/hip_fp16.h>
#include <math.h>

#define N_NODES 102400
#define N_EDGES 1638400
#define NB 100            // coarse buckets: node range 1024 (102400/1024)
#define PB 256            // partition blocks
#define EPB (N_EDGES/PB)  // 6400 edges per partition block
#define NSL 8             // src slices (src>>14 -> 0..6 used)

// ---- pass A: per-block coarse histograms of dst>>10 and src>>10 (LDS, atomic-free globally) ----
__global__ __launch_bounds__(256) void histA_kernel(const int* __restrict__ src, const int* __restrict__ dst,
                                                    int* __restrict__ histD, int* __restrict__ histS) {
    __shared__ int hD[NB], hS[NB];
    int tid = threadIdx.x;
    if (tid < NB) { hD[tid] = 0; hS[tid] = 0; }
    __syncthreads();
    int base = blockIdx.x * EPB;
    for (int i = tid; i < EPB; i += 256) {
        atomicAdd(&hD[dst[base + i] >> 10], 1);   // LDS atomic (CU-local)
        atomicAdd(&hS[src[base + i] >> 10], 1);
    }
    __syncthreads();
    if (tid < NB) {
        histD[blockIdx.x * NB + tid] = hD[tid];
        histS[blockIdx.x * NB + tid] = hS[tid];
    }
}

// ---- pass B: scan block-bucket matrices -> per-(block,bucket) offsets + coarse bases ----
__global__ __launch_bounds__(256) void scanB_kernel(const int* __restrict__ histD, const int* __restrict__ histS,
                                                    int* __restrict__ offD, int* __restrict__ offS,
                                                    int* __restrict__ coarseD, int* __restrict__ coarseS) {
    __shared__ int totD[NB], totS[NB], baseD[NB + 1], baseS[NB + 1];
    int t = threadIdx.x;
    if (t < NB) { int s = 0; for (int k = 0; k < PB; k++) s += histD[k * NB + t]; totD[t] = s; }
    else if (t >= 128 && t < 128 + NB) { int j = t - 128; int s = 0; for (int k = 0; k < PB; k++) s += histS[k * NB + j]; totS[j] = s; }
    __syncthreads();
    if (t == 0)   { int r = 0; for (int j = 0; j < NB; j++) { baseD[j] = r; r += totD[j]; } baseD[NB] = r; }
    if (t == 128) { int r = 0; for (int j = 0; j < NB; j++) { baseS[j] = r; r += totS[j]; } baseS[NB] = r; }
    __syncthreads();
    if (t < NB) { int r = baseD[t]; for (int k = 0; k < PB; k++) { offD[k * NB + t] = r; r += histD[k * NB + t]; } }
    else if (t >= 128 && t < 128 + NB) { int j = t - 128; int r = baseS[j]; for (int k = 0; k < PB; k++) { offS[k * NB + j] = r; r += histS[k * NB + j]; } }
    if (t <= NB) coarseD[t] = baseD[t];
    if (t >= 128 && t <= 128 + NB) coarseS[t - 128] = baseS[t - 128];
}

// ---- pass C: partition edges into coarse buckets (LDS cursors, disjoint global slices) ----
__global__ __launch_bounds__(256) void partC_kernel(const int* __restrict__ src, const int* __restrict__ dst,
                                                    const float* __restrict__ ew,
                                                    const int* __restrict__ offD, const int* __restrict__ offS,
                                                    int2* __restrict__ partD, int* __restrict__ partS) {
    __shared__ int cD[NB], cS[NB];
    int tid = threadIdx.x;
    if (tid < NB) { cD[tid] = offD[blockIdx.x * NB + tid]; cS[tid] = offS[blockIdx.x * NB + tid]; }
    __syncthreads();
    int base = blockIdx.x * EPB;
    for (int i = tid; i < EPB; i += 256) {
        int s = src[base + i], d = dst[base + i];
        float w = ew[base + i];
        int p = atomicAdd(&cD[d >> 10], 1);              // LDS atomic
        partD[p] = make_int2(s | ((d & 1023) << 17), __float_as_int(w));
        int q = atomicAdd(&cS[s >> 10], 1);              // LDS atomic
        partS[q] = s & 1023;
    }
}

// ---- pass D2: per src-bucket fine histogram -> outdeg_inv ----
__global__ __launch_bounds__(1024) void fineS_kernel(const int* __restrict__ partS, const int* __restrict__ coarseS,
                                                     float* __restrict__ outdeg_inv) {
    __shared__ int hist[1024];
    int tid = threadIdx.x;
    hist[tid] = 0;
    __syncthreads();
    int beg = coarseS[blockIdx.x], end = coarseS[blockIdx.x + 1];
    for (int i = beg + tid; i < end; i += 1024) atomicAdd(&hist[partS[i]], 1);
    __syncthreads();
    outdeg_inv[blockIdx.x * 1024 + tid] = 1.0f / sqrtf((float)max(hist[tid], 1));
}

// ---- pass D: per dst-bucket fine sort keyed by (node, src>>14) -> row_off, indeg_inv,
//      final CSR with each row's edges grouped into src slices (L2-locality for gathers) ----
__global__ __launch_bounds__(1024) void fineD_kernel(const int2* __restrict__ partD, const int* __restrict__ coarseD,
                                                     const float* __restrict__ outdeg_inv,
                                                     int2* __restrict__ edge_perm, int* __restrict__ row_off,
                                                     float* __restrict__ indeg_inv) {
    __shared__ int hist[NSL * 1024];   // [slice][node]; becomes cursor after scan (32KB)
    __shared__ int wsum[16];
    int tid = threadIdx.x, lane = tid & 63, wid = tid >> 6;
    #pragma unroll
    for (int j = 0; j < NSL; ++j) hist[j * 1024 + tid] = 0;
    __syncthreads();
    int beg = coarseD[blockIdx.x], end = coarseD[blockIdx.x + 1];
    for (int i = beg + tid; i < end; i += 1024) {
        int xk = partD[i].x;
        int node = (xk >> 17) & 1023;
        int sl = (xk & 0x1FFFF) >> 14;      // 0..6
        atomicAdd(&hist[sl * 1024 + node], 1);
    }
    __syncthreads();
    // per-node total v + in-node slice prefix
    int pre[NSL];
    int v = 0;
    #pragma unroll
    for (int j = 0; j < NSL; ++j) { pre[j] = v; v += hist[j * 1024 + tid]; }
    // block-wide exclusive scan of node totals
    int x = v;
    #pragma unroll
    for (int s = 1; s < 64; s <<= 1) { int t = __shfl_up(x, s, 64); if (lane >= s) x += t; }
    if (lane == 63) wsum[wid] = x;
    __syncthreads();
    if (wid == 0) {
        int ws = (lane < 16) ? wsum[lane] : 0;
        int y = ws;
        #pragma unroll
        for (int s = 1; s < 16; s <<= 1) { int t = __shfl_up(y, s, 64); if (lane >= s) y += t; }
        if (lane < 16) wsum[lane] = y - ws;
    }
    __syncthreads();
    int node_start = beg + wsum[wid] + x - v;   // exclusive scan for this node
    int node = blockIdx.x * 1024 + tid;
    row_off[node] = node_start;
    indeg_inv[node] = 1.0f / sqrtf((float)max(v, 1));
    if (blockIdx.x == NB - 1 && tid == 0) row_off[N_NODES] = N_EDGES;
    __syncthreads();   // wsum reuse barrier (hist not yet overwritten: convert to cursors now)
    #pragma unroll
    for (int j = 0; j < NSL; ++j) hist[j * 1024 + tid] = node_start + pre[j];
    __syncthreads();
    for (int i = beg + tid; i < end; i += 1024) {
        int2 t2 = partD[i];
        int nd = (t2.x >> 17) & 1023, s = t2.x & 0x1FFFF;
        int sl = s >> 14;
        int p = atomicAdd(&hist[sl * 1024 + nd], 1);    // LDS cursor
        float w = __int_as_float(t2.y) * outdeg_inv[s];
        edge_perm[p] = make_int2(s, __float_as_int(w));
    }
}

// ---------------- register-tiled node transform: out(fp16) = h @ W ----------------
template<int K, int C, int RN>
__global__ __launch_bounds__(256) void gemm_tile_kernel(
    const float* __restrict__ h, const float* __restrict__ W, __half* __restrict__ out) {
    constexpr int BM = 64;
    constexpr int RM = 4;
    constexpr int KC = 64;
    constexpr int TX = C / RN;               // 16
    constexpr int TY = BM / RM;              // 16
    static_assert(TX * TY == 256, "bad tile");
    static_assert(RN == 4, "fp16 epilogue assumes RN==4");

    __shared__ float Ws[K * C];
    __shared__ float Hs[KC][BM + 4];

    const int tid = threadIdx.x;
    const long brow = (long)blockIdx.x * BM;

    for (int i = tid; i < K * C; i += 256) Ws[i] = W[i];

    const int tx = tid % TX;
    const int ty = tid / TX;
    float acc[RM][RN] = {};

    const int lr = tid % 16;
    const int lk = tid / 16;

    for (int kc = 0; kc < K; kc += KC) {
        __syncthreads();
        #pragma unroll
        for (int p0 = 0; p0 < BM; p0 += 16) {
            const int r = p0 + lr;
            const float4 hv = *(const float4*)(h + (brow + r) * K + kc + lk * 4);
            Hs[lk * 4 + 0][r] = hv.x;
            Hs[lk * 4 + 1][r] = hv.y;
            Hs[lk * 4 + 2][r] = hv.z;
            Hs[lk * 4 + 3][r] = hv.w;
        }
        __syncthreads();

        #pragma unroll
        for (int k = 0; k < KC; ++k) {
            const float4 a4 = *(const float4*)&Hs[k][ty * RM];
            const float av[RM] = {a4.x, a4.y, a4.z, a4.w};
            float b[RN];
            *(float4*)b = *(const float4*)&Ws[(kc + k) * C + tx * RN];
            #pragma unroll
            for (int i = 0; i < RM; ++i)
                #pragma unroll
                for (int j = 0; j < RN; ++j)
                    acc[i][j] += av[i] * b[j];
        }
    }

    #pragma unroll
    for (int i = 0; i < RM; ++i) {
        const long row = brow + ty * RM + i;
        __half2 p01 = __floats2half2_rn(acc[i][0], acc[i][1]);
        __half2 p23 = __floats2half2_rn(acc[i][2], acc[i][3]);
        int2 packed = make_int2(*(int*)&p01, *(int*)&p23);
        *(int2*)(out + row * C + tx * RN) = packed;   // 8B coalesced store
    }
}

// ---------------- layer-0 aggregation (fp16 gather) + fused layer-1 transform ----------------
// One wave per node. lane = eslot(0..3) x chunk(0..15); main loop 16 edges/iter, clamp-free
// (4 independent 8B gathers in flight); clamped 4-edge tail. fp32 accumulate.
__global__ __launch_bounds__(256) void agg64_gemm_kernel(
    const __half* __restrict__ ht, const int* __restrict__ row_off,
    const int2* __restrict__ ep, const float* __restrict__ indeg_inv,
    const float* __restrict__ b0, const float* __restrict__ W1,
    __half* __restrict__ ht1, int N) {
    __shared__ float W1s[64 * 32];
    __shared__ float h1s[4][64];
    int tid = threadIdx.x;
    {   // vectorized W1 staging: 2 x float4 per thread
        const float4* W1v = (const float4*)W1;
        float4* W1sv = (float4*)W1s;
        W1sv[tid] = W1v[tid];
        W1sv[tid + 256] = W1v[tid + 256];
    }
    __syncthreads();

    int wave = (blockIdx.x * blockDim.x + tid) >> 6;
    int lane = tid & 63;
    if (wave >= N) return;
    int chunk = lane & 15;       // channels 4*chunk .. 4*chunk+3
    int eslot = lane >> 4;       // 0..3
    int beg = row_off[wave], end = row_off[wave + 1];

    float4 a0 = {0, 0, 0, 0}, a1 = {0, 0, 0, 0};
    int e = beg;
    for (; e + 16 <= end; e += 16) {
        int2 d0 = ep[e + eslot];
        int2 d1 = ep[e + 4 + eslot];
        int2 d2 = ep[e + 8 + eslot];
        int2 d3 = ep[e + 12 + eslot];
        int2 r0 = *(const int2*)(ht + (long)d0.x * 64 + chunk * 4);
        int2 r1 = *(const int2*)(ht + (long)d1.x * 64 + chunk * 4);
        int2 r2 = *(const int2*)(ht + (long)d2.x * 64 + chunk * 4);
        int2 r3 = *(const int2*)(ht + (long)d3.x * 64 + chunk * 4);
        float w0 = __int_as_float(d0.y), w1 = __int_as_float(d1.y);
        float w2 = __int_as_float(d2.y), w3 = __int_as_float(d3.y);
        float2 f0a = __half22float2(*(__half2*)&r0.x), f0b = __half22float2(*(__half2*)&r0.y);
        float2 f1a = __half22float2(*(__half2*)&r1.x), f1b = __half22float2(*(__half2*)&r1.y);
        float2 f2a = __half22float2(*(__half2*)&r2.x), f2b = __half22float2(*(__half2*)&r2.y);
        float2 f3a = __half22float2(*(__half2*)&r3.x), f3b = __half22float2(*(__half2*)&r3.y);
        a0.x += f0a.x * w0; a0.y += f0a.y * w0; a0.z += f0b.x * w0; a0.w += f0b.y * w0;
        a1.x += f1a.x * w1; a1.y += f1a.y * w1; a1.z += f1b.x * w1; a1.w += f1b.y * w1;
        a0.x += f2a.x * w2; a0.y += f2a.y * w2; a0.z += f2b.x * w2; a0.w += f2b.y * w2;
        a1.x += f3a.x * w3; a1.y += f3a.y * w3; a1.z += f3b.x * w3; a1.w += f3b.y * w3;
    }
    for (; e < end; e += 4) {                    // clamped tail, <=15 edges
        int ei = e + eslot;
        int2 d0 = ep[min(ei, end - 1)];
        float w0 = (ei < end) ? __int_as_float(d0.y) : 0.0f;
        int2 r0 = *(const int2*)(ht + (long)d0.x * 64 + chunk * 4);
        float2 f0a = __half22float2(*(__half2*)&r0.x), f0b = __half22float2(*(__half2*)&r0.y);
        a0.x += f0a.x * w0; a0.y += f0a.y * w0; a0.z += f0b.x * w0; a0.w += f0b.y * w0;
    }
    a0.x += a1.x; a0.y += a1.y; a0.z += a1.z; a0.w += a1.w;
    // butterfly-reduce across eslot (lane bits 4,5)
    #pragma unroll
    for (int s = 16; s <= 32; s <<= 1) {
        a0.x += __shfl_xor(a0.x, s, 64);
        a0.y += __shfl_xor(a0.y, s, 64);
        a0.z += __shfl_xor(a0.z, s, 64);
        a0.w += __shfl_xor(a0.w, s, 64);
    }
    int wv = tid >> 6;
    if (eslot == 0) {
        float sc = indeg_inv[wave];
        float4 b = *(const float4*)(b0 + chunk * 4);
        float4 v;
        v.x = tanhf(a0.x * sc + b.x);
        v.y = tanhf(a0.y * sc + b.y);
        v.z = tanhf(a0.z * sc + b.z);
        v.w = tanhf(a0.w * sc + b.w);
        *(float4*)&h1s[wv][chunk * 4] = v;   // one ds_write_b128
    }
    // fused 64->32: lane = (c, half); k in [32*half, 32*half+32)
    int c = lane & 31, half = lane >> 5;
    float t = 0.0f;
    #pragma unroll
    for (int j4 = 0; j4 < 8; ++j4) {
        int k = half * 32 + j4 * 4;
        float4 hh = *(const float4*)&h1s[wv][k];    // broadcast read
        t += hh.x * W1s[(k + 0) * 32 + c];
        t += hh.y * W1s[(k + 1) * 32 + c];
        t += hh.z * W1s[(k + 2) * 32 + c];
        t += hh.w * W1s[(k + 3) * 32 + c];
    }
    t += __shfl_xor(t, 32, 64);
    if (half == 0) ht1[(long)wave * 32 + c] = __float2half_rn(t);
}

// C=32 agg (fp16 gather) + fused K=32->1: lane = eslot(0..7) x chunk(0..7);
// main loop 16 edges/iter clamp-free, clamped 8-edge tail.
__global__ void agg32_dot_kernel(const __half* __restrict__ ht, const int* __restrict__ row_off,
                                 const int2* __restrict__ ep,
                                 const float* __restrict__ indeg_inv, const float* __restrict__ bias,
                                 const float* __restrict__ W2, float* __restrict__ ht2, int N) {
    int wave = (blockIdx.x * blockDim.x + threadIdx.x) >> 6;
    int lane = threadIdx.x & 63;
    if (wave >= N) return;
    int chunk = lane & 7;        // channels 4*chunk .. 4*chunk+3
    int eslot = lane >> 3;       // 0..7
    int beg = row_off[wave], end = row_off[wave + 1];
    float4 a0 = {0, 0, 0, 0}, a1 = {0, 0, 0, 0};
    int e = beg;
    for (; e + 16 <= end; e += 16) {
        int2 d0 = ep[e + eslot];
        int2 d1 = ep[e + 8 + eslot];
        int2 r0 = *(const int2*)(ht + (long)d0.x * 32 + chunk * 4);
        int2 r1 = *(const int2*)(ht + (long)d1.x * 32 + chunk * 4);
        float w0 = __int_as_float(d0.y), w1 = __int_as_float(d1.y);
        float2 f0a = __half22float2(*(__half2*)&r0.x), f0b = __half22float2(*(__half2*)&r0.y);
        float2 f1a = __half22float2(*(__half2*)&r1.x), f1b = __half22float2(*(__half2*)&r1.y);
        a0.x += f0a.x * w0; a0.y += f0a.y * w0; a0.z += f0b.x * w0; a0.w += f0b.y * w0;
        a1.x += f1a.x * w1; a1.y += f1a.y * w1; a1.z += f1b.x * w1; a1.w += f1b.y * w1;
    }
    for (; e < end; e += 8) {                    // clamped tail
        int ei = e + eslot;
        int2 d0 = ep[min(ei, end - 1)];
        float w0 = (ei < end) ? __int_as_float(d0.y) : 0.0f;
        int2 r0 = *(const int2*)(ht + (long)d0.x * 32 + chunk * 4);
        float2 f0a = __half22float2(*(__half2*)&r0.x), f0b = __half22float2(*(__half2*)&r0.y);
        a0.x += f0a.x * w0; a0.y += f0a.y * w0; a0.z += f0b.x * w0; a0.w += f0b.y * w0;
    }
    a0.x += a1.x; a0.y += a1.y; a0.z += a1.z; a0.w += a1.w;
    // butterfly-reduce across eslot (lane bits 3,4,5)
    #pragma unroll
    for (int s = 8; s <= 32; s <<= 1) {
        a0.x += __shfl_xor(a0.x, s, 64);
        a0.y += __shfl_xor(a0.y, s, 64);
        a0.z += __shfl_xor(a0.z, s, 64);
        a0.w += __shfl_xor(a0.w, s, 64);
    }
    float sc = indeg_inv[wave];
    float4 b = *(const float4*)(bias + chunk * 4);
    float4 w2 = *(const float4*)(W2 + chunk * 4);
    float t = tanhf(a0.x * sc + b.x) * w2.x
            + tanhf(a0.y * sc + b.y) * w2.y
            + tanhf(a0.z * sc + b.z) * w2.z
            + tanhf(a0.w * sc + b.w) * w2.w;
    t += __shfl_xor(t, 1, 64);
    t += __shfl_xor(t, 2, 64);
    t += __shfl_xor(t, 4, 64);
    if (lane == 0) ht2[wave] = t;
}

// C=1 final aggregation: 16 lanes per node (4 nodes/wave); coalesced edge reads
__global__ void agg1_kernel(const float* __restrict__ ht2, const int* __restrict__ row_off,
                            const int2* __restrict__ ep,
                            const float* __restrict__ indeg_inv, const float* __restrict__ bias,
                            float* __restrict__ out, int N) {
    int wave = (blockIdx.x * blockDim.x + threadIdx.x) >> 6;
    int lane = threadIdx.x & 63;
    int sub = lane >> 4;         // 0..3
    int slot = lane & 15;
    int node = wave * 4 + sub;
    if (node >= N) return;
    int beg = row_off[node], end = row_off[node + 1];
    float acc = 0.0f;
    for (int e = beg + slot; e < end; e += 16) {
        int2 t = ep[e];
        acc += ht2[t.x] * __int_as_float(t.y);
    }
    #pragma unroll
    for (int s = 1; s <= 8; s <<= 1) acc += __shfl_xor(acc, s, 64);  // within 16-lane group
    if (slot == 0) out[node] = acc * indeg_inv[node] + bias[0];
}

extern "C" void kernel_launch(void* const* d_in, const int* in_sizes, int n_in,
                              void* d_out, int out_size, void* d_ws, size_t ws_size,
                              hipStream_t stream) {
    const float* b_z = (const float*)d_in[0];
    const int*   src = (const int*)d_in[1];
    const int*   dst = (const int*)d_in[2];
    const float* ew  = (const float*)d_in[3];
    const float* W0 = (const float*)d_in[5];
    const float* b0 = (const float*)d_in[6];
    const float* W1 = (const float*)d_in[7];
    const float* b1 = (const float*)d_in[8];
    const float* W2 = (const float*)d_in[9];
    const float* b2 = (const float*)d_in[10];
    float* out = (float*)d_out;

    const int N = N_NODES;
    const int E = N_EDGES;

    // workspace layout (16B-aligned segments)
    char* p = (char*)d_ws;
    int*   row_off    = (int*)p;            p += (size_t)(N + 4) * 4;
    float* outdeg_inv = (float*)p;          p += (size_t)N * 4;
    float* indeg_inv  = (float*)p;          p += (size_t)N * 4;
    int*   histD      = (int*)p;            p += (size_t)PB * NB * 4;
    int*   histS      = (int*)p;            p += (size_t)PB * NB * 4;
    int*   offD       = (int*)p;            p += (size_t)PB * NB * 4;
    int*   offS       = (int*)p;            p += (size_t)PB * NB * 4;
    int*   coarseD    = (int*)p;            p += (size_t)(NB + 4) * 4;
    int*   coarseS    = (int*)p;            p += (size_t)(NB + 4) * 4;
    int2*  edge_perm  = (int2*)p;           p += (size_t)E * 8;
    float* bufA       = (float*)p;          p += (size_t)N * 64 * 4;
    float* bufB       = (float*)p;
    // aliases with disjoint lifetimes:
    int2*   partD = (int2*)bufA;    // dead after fineD; gemm0 then writes bufA (ht fp16, 13MB)
    int*    partS = (int*)bufB;     // dead after fineS; agg64_gemm then writes bufB (ht1 fp16)
    __half* ht    = (__half*)bufA;  // N x 64 fp16, written by gemm0, read by agg64_gemm
    __half* ht1   = (__half*)bufB;  // N x 32 fp16, written by agg64_gemm, read by agg32_dot
    float*  ht2   = bufA;           // N x 1 fp32, written by agg32_dot (ht dead by then)

    // ---- atomic-free CSR build (two-level counting sort; rows slice-grouped by src>>14) ----
    histA_kernel<<<PB, 256, 0, stream>>>(src, dst, histD, histS);
    scanB_kernel<<<1, 256, 0, stream>>>(histD, histS, offD, offS, coarseD, coarseS);
    partC_kernel<<<PB, 256, 0, stream>>>(src, dst, ew, offD, offS, partD, partS);
    fineS_kernel<<<NB, 1024, 0, stream>>>(partS, coarseS, outdeg_inv);
    fineD_kernel<<<NB, 1024, 0, stream>>>(partD, coarseD, outdeg_inv, edge_perm, row_off, indeg_inv);

    // ---- layer 0 transform: 128 -> 64, fp16 out ----
    gemm_tile_kernel<128, 64, 4><<<N / 64, 256, 0, stream>>>(b_z, W0, ht);

    // ---- layer 0 aggregation + tanh + fused layer-1 transform (64 -> 32), fp16 out ----
    agg64_gemm_kernel<<<N / 4, 256, 0, stream>>>(ht, row_off, edge_perm, indeg_inv, b0, W1, ht1, N);

    // ---- layer 1 aggregation + tanh + fused layer-2 transform (32 -> 1) ----
    agg32_dot_kernel<<<N / 4, 256, 0, stream>>>(ht1, row_off, edge_perm, indeg_inv, b1, W2, ht2, N);

    // ---- layer 2 aggregation -> out ----
    agg1_kernel<<<N / 16, 256, 0, stream>>>(ht2, row_off, edge_perm, indeg_inv, b2, out, N);
}

// Round 12
// 338.931 us; speedup vs baseline: 1.0165x; 1.0165x over previous
//
#include <hip/hip_runtime.h>
#include <hip/hip_fp16.h>
#include <math.h>

#define N_NODES 102400
#define N_EDGES 1638400
#define NB 100            // coarse buckets: node range 1024 (102400/1024)
#define PB 256            // partition blocks
#define EPB (N_EDGES/PB)  // 6400 edges per partition block

union H4 { int2 i2; __half h[4]; };

// ---- pass A: per-block coarse histograms of dst>>10 and src>>10 (LDS, atomic-free globally) ----
__global__ __launch_bounds__(256) void histA_kernel(const int* __restrict__ src, const int* __restrict__ dst,
                                                    int* __restrict__ histD, int* __restrict__ histS) {
    __shared__ int hD[NB], hS[NB];
    int tid = threadIdx.x;
    if (tid < NB) { hD[tid] = 0; hS[tid] = 0; }
    __syncthreads();
    int base = blockIdx.x * EPB;
    for (int i = tid; i < EPB; i += 256) {
        atomicAdd(&hD[dst[base + i] >> 10], 1);   // LDS atomic (CU-local)
        atomicAdd(&hS[src[base + i] >> 10], 1);
    }
    __syncthreads();
    if (tid < NB) {
        histD[blockIdx.x * NB + tid] = hD[tid];
        histS[blockIdx.x * NB + tid] = hS[tid];
    }
}

// ---- pass B: scan block-bucket matrices -> per-(block,bucket) offsets + coarse bases ----
__global__ __launch_bounds__(256) void scanB_kernel(const int* __restrict__ histD, const int* __restrict__ histS,
                                                    int* __restrict__ offD, int* __restrict__ offS,
                                                    int* __restrict__ coarseD, int* __restrict__ coarseS) {
    __shared__ int totD[NB], totS[NB], baseD[NB + 1], baseS[NB + 1];
    int t = threadIdx.x;
    if (t < NB) { int s = 0; for (int k = 0; k < PB; k++) s += histD[k * NB + t]; totD[t] = s; }
    else if (t >= 128 && t < 128 + NB) { int j = t - 128; int s = 0; for (int k = 0; k < PB; k++) s += histS[k * NB + j]; totS[j] = s; }
    __syncthreads();
    if (t == 0)   { int r = 0; for (int j = 0; j < NB; j++) { baseD[j] = r; r += totD[j]; } baseD[NB] = r; }
    if (t == 128) { int r = 0; for (int j = 0; j < NB; j++) { baseS[j] = r; r += totS[j]; } baseS[NB] = r; }
    __syncthreads();
    if (t < NB) { int r = baseD[t]; for (int k = 0; k < PB; k++) { offD[k * NB + t] = r; r += histD[k * NB + t]; } }
    else if (t >= 128 && t < 128 + NB) { int j = t - 128; int r = baseS[j]; for (int k = 0; k < PB; k++) { offS[k * NB + j] = r; r += histS[k * NB + j]; } }
    if (t <= NB) coarseD[t] = baseD[t];
    if (t >= 128 && t <= 128 + NB) coarseS[t - 128] = baseS[t - 128];
}

// ---- pass C: partition edges into coarse buckets (LDS cursors, disjoint global slices) ----
__global__ __launch_bounds__(256) void partC_kernel(const int* __restrict__ src, const int* __restrict__ dst,
                                                    const float* __restrict__ ew,
                                                    const int* __restrict__ offD, const int* __restrict__ offS,
                                                    int2* __restrict__ partD, int* __restrict__ partS) {
    __shared__ int cD[NB], cS[NB];
    int tid = threadIdx.x;
    if (tid < NB) { cD[tid] = offD[blockIdx.x * NB + tid]; cS[tid] = offS[blockIdx.x * NB + tid]; }
    __syncthreads();
    int base = blockIdx.x * EPB;
    for (int i = tid; i < EPB; i += 256) {
        int s = src[base + i], d = dst[base + i];
        float w = ew[base + i];
        int p = atomicAdd(&cD[d >> 10], 1);              // LDS atomic
        partD[p] = make_int2(s | ((d & 1023) << 17), __float_as_int(w));
        int q = atomicAdd(&cS[s >> 10], 1);              // LDS atomic
        partS[q] = s & 1023;
    }
}

// ---- pass D2: per src-bucket fine histogram -> outdeg_inv ----
__global__ __launch_bounds__(1024) void fineS_kernel(const int* __restrict__ partS, const int* __restrict__ coarseS,
                                                     float* __restrict__ outdeg_inv) {
    __shared__ int hist[1024];
    int tid = threadIdx.x;
    hist[tid] = 0;
    __syncthreads();
    int beg = coarseS[blockIdx.x], end = coarseS[blockIdx.x + 1];
    for (int i = beg + tid; i < end; i += 1024) atomicAdd(&hist[partS[i]], 1);
    __syncthreads();
    outdeg_inv[blockIdx.x * 1024 + tid] = 1.0f / sqrtf((float)max(hist[tid], 1));
}

// ---- pass D: per dst-bucket fine sort -> row_off, indeg_inv, final CSR (weights pre-scaled) ----
__global__ __launch_bounds__(1024) void fineD_kernel(const int2* __restrict__ partD, const int* __restrict__ coarseD,
                                                     const float* __restrict__ outdeg_inv,
                                                     int2* __restrict__ edge_perm, int* __restrict__ row_off,
                                                     float* __restrict__ indeg_inv) {
    __shared__ int hist[1024], cursor[1024];
    __shared__ int wsum[16];
    int tid = threadIdx.x, lane = tid & 63, wid = tid >> 6;
    hist[tid] = 0;
    __syncthreads();
    int beg = coarseD[blockIdx.x], end = coarseD[blockIdx.x + 1];
    for (int i = beg + tid; i < end; i += 1024) atomicAdd(&hist[(partD[i].x >> 17) & 1023], 1);
    __syncthreads();
    // exclusive scan of hist across the block
    int v = hist[tid];
    int x = v;
    #pragma unroll
    for (int s = 1; s < 64; s <<= 1) { int t = __shfl_up(x, s, 64); if (lane >= s) x += t; }
    if (lane == 63) wsum[wid] = x;
    __syncthreads();
    if (wid == 0) {
        int ws = (lane < 16) ? wsum[lane] : 0;
        int y = ws;
        #pragma unroll
        for (int s = 1; s < 16; s <<= 1) { int t = __shfl_up(y, s, 64); if (lane >= s) y += t; }
        if (lane < 16) wsum[lane] = y - ws;
    }
    __syncthreads();
    int ex = wsum[wid] + x - v;                 // exclusive scan value for this node
    cursor[tid] = beg + ex;
    int node = blockIdx.x * 1024 + tid;
    row_off[node] = beg + ex;
    indeg_inv[node] = 1.0f / sqrtf((float)max(v, 1));
    if (blockIdx.x == NB - 1 && tid == 0) row_off[N_NODES] = N_EDGES;
    __syncthreads();
    for (int i = beg + tid; i < end; i += 1024) {
        int2 t2 = partD[i];
        int d = (t2.x >> 17) & 1023, s = t2.x & 0x1FFFF;
        int p = atomicAdd(&cursor[d], 1);       // LDS atomic
        float w = __int_as_float(t2.y) * outdeg_inv[s];
        edge_perm[p] = make_int2(s, __float_as_int(w));
    }
}

// ---------------- register-tiled node transform: out(fp16) = h @ W ----------------
template<int K, int C, int RN>
__global__ __launch_bounds__(256) void gemm_tile_kernel(
    const float* __restrict__ h, const float* __restrict__ W, __half* __restrict__ out) {
    constexpr int BM = 64;
    constexpr int RM = 4;
    constexpr int KC = 64;
    constexpr int TX = C / RN;               // 16
    constexpr int TY = BM / RM;              // 16
    static_assert(TX * TY == 256, "bad tile");
    static_assert(RN == 4, "fp16 epilogue assumes RN==4");

    __shared__ float Ws[K * C];
    __shared__ float Hs[KC][BM + 4];

    const int tid = threadIdx.x;
    const long brow = (long)blockIdx.x * BM;

    for (int i = tid; i < K * C; i += 256) Ws[i] = W[i];

    const int tx = tid % TX;
    const int ty = tid / TX;
    float acc[RM][RN] = {};

    const int lr = tid % 16;
    const int lk = tid / 16;

    for (int kc = 0; kc < K; kc += KC) {
        __syncthreads();
        #pragma unroll
        for (int p0 = 0; p0 < BM; p0 += 16) {
            const int r = p0 + lr;
            const float4 hv = *(const float4*)(h + (brow + r) * K + kc + lk * 4);
            Hs[lk * 4 + 0][r] = hv.x;
            Hs[lk * 4 + 1][r] = hv.y;
            Hs[lk * 4 + 2][r] = hv.z;
            Hs[lk * 4 + 3][r] = hv.w;
        }
        __syncthreads();

        #pragma unroll
        for (int k = 0; k < KC; ++k) {
            const float4 a4 = *(const float4*)&Hs[k][ty * RM];
            const float av[RM] = {a4.x, a4.y, a4.z, a4.w};
            float b[RN];
            *(float4*)b = *(const float4*)&Ws[(kc + k) * C + tx * RN];
            #pragma unroll
            for (int i = 0; i < RM; ++i)
                #pragma unroll
                for (int j = 0; j < RN; ++j)
                    acc[i][j] += av[i] * b[j];
        }
    }

    #pragma unroll
    for (int i = 0; i < RM; ++i) {
        const long row = brow + ty * RM + i;
        __half2 p01 = __floats2half2_rn(acc[i][0], acc[i][1]);
        __half2 p23 = __floats2half2_rn(acc[i][2], acc[i][3]);
        int2 packed = make_int2(*(int*)&p01, *(int*)&p23);
        *(int2*)(out + row * C + tx * RN) = packed;   // 8B coalesced store
    }
}

// ---------------- layer-0 aggregation (fp16 gather) + fused layer-1 transform ----------------
// One wave per node. lane = eslot(0..3) x chunk(0..15); 8 edges/iter (2 loads in flight).
// fp16 operands consumed via fma_mix (no explicit cvt); 32-bit table offsets.
__global__ __launch_bounds__(256) void agg64_gemm_kernel(
    const __half* __restrict__ ht, const int* __restrict__ row_off,
    const int2* __restrict__ ep, const float* __restrict__ indeg_inv,
    const float* __restrict__ b0, const float* __restrict__ W1,
    __half* __restrict__ ht1, int N) {
    __shared__ float W1s[64 * 32];
    __shared__ float h1s[4][64];
    int tid = threadIdx.x;
    {   // vectorized W1 staging: 2 x float4 per thread
        const float4* W1v = (const float4*)W1;
        float4* W1sv = (float4*)W1s;
        W1sv[tid] = W1v[tid];
        W1sv[tid + 256] = W1v[tid + 256];
    }
    __syncthreads();

    int wave = (blockIdx.x * blockDim.x + tid) >> 6;
    int lane = tid & 63;
    if (wave >= N) return;
    int chunk = lane & 15;       // channels 4*chunk .. 4*chunk+3
    int eslot = lane >> 4;       // 0..3
    int beg = row_off[wave], end = row_off[wave + 1];
    const char* htb = (const char*)ht;
    unsigned coff = (unsigned)(chunk << 3);

    float4 a0 = {0, 0, 0, 0}, a1 = {0, 0, 0, 0};
    for (int e = beg; e < end; e += 8) {
        int ei0 = e + eslot, ei1 = e + 4 + eslot;
        int2 d0 = ep[min(ei0, end - 1)];
        int2 d1 = ep[min(ei1, end - 1)];
        float w0 = (ei0 < end) ? __int_as_float(d0.y) : 0.0f;
        float w1 = (ei1 < end) ? __int_as_float(d1.y) : 0.0f;
        H4 r0, r1;
        r0.i2 = *(const int2*)(htb + (((unsigned)d0.x << 7) | coff));
        r1.i2 = *(const int2*)(htb + (((unsigned)d1.x << 7) | coff));
        a0.x = fmaf(__half2float(r0.h[0]), w0, a0.x);
        a0.y = fmaf(__half2float(r0.h[1]), w0, a0.y);
        a0.z = fmaf(__half2float(r0.h[2]), w0, a0.z);
        a0.w = fmaf(__half2float(r0.h[3]), w0, a0.w);
        a1.x = fmaf(__half2float(r1.h[0]), w1, a1.x);
        a1.y = fmaf(__half2float(r1.h[1]), w1, a1.y);
        a1.z = fmaf(__half2float(r1.h[2]), w1, a1.z);
        a1.w = fmaf(__half2float(r1.h[3]), w1, a1.w);
    }
    a0.x += a1.x; a0.y += a1.y; a0.z += a1.z; a0.w += a1.w;
    // butterfly-reduce across eslot (lane bits 4,5)
    #pragma unroll
    for (int s = 16; s <= 32; s <<= 1) {
        a0.x += __shfl_xor(a0.x, s, 64);
        a0.y += __shfl_xor(a0.y, s, 64);
        a0.z += __shfl_xor(a0.z, s, 64);
        a0.w += __shfl_xor(a0.w, s, 64);
    }
    int wv = tid >> 6;
    if (eslot == 0) {
        float sc = indeg_inv[wave];
        float4 b = *(const float4*)(b0 + chunk * 4);
        float4 v;
        v.x = tanhf(a0.x * sc + b.x);
        v.y = tanhf(a0.y * sc + b.y);
        v.z = tanhf(a0.z * sc + b.z);
        v.w = tanhf(a0.w * sc + b.w);
        *(float4*)&h1s[wv][chunk * 4] = v;   // one ds_write_b128
    }
    // fused 64->32: lane = (c, half); k in [32*half, 32*half+32)
    int c = lane & 31, half = lane >> 5;
    float t = 0.0f;
    #pragma unroll
    for (int j4 = 0; j4 < 8; ++j4) {
        int k = half * 32 + j4 * 4;
        float4 hh = *(const float4*)&h1s[wv][k];    // broadcast read
        t += hh.x * W1s[(k + 0) * 32 + c];
        t += hh.y * W1s[(k + 1) * 32 + c];
        t += hh.z * W1s[(k + 2) * 32 + c];
        t += hh.w * W1s[(k + 3) * 32 + c];
    }
    t += __shfl_xor(t, 32, 64);
    if (half == 0) ht1[(long)wave * 32 + c] = __float2half_rn(t);
}

// C=32 agg (fp16 gather) + fused K=32->1: lane = eslot(0..7) x chunk(0..7); 16 edges/iter
__global__ void agg32_dot_kernel(const __half* __restrict__ ht, const int* __restrict__ row_off,
                                 const int2* __restrict__ ep,
                                 const float* __restrict__ indeg_inv, const float* __restrict__ bias,
                                 const float* __restrict__ W2, float* __restrict__ ht2, int N) {
    int wave = (blockIdx.x * blockDim.x + threadIdx.x) >> 6;
    int lane = threadIdx.x & 63;
    if (wave >= N) return;
    int chunk = lane & 7;        // channels 4*chunk .. 4*chunk+3
    int eslot = lane >> 3;       // 0..7
    int beg = row_off[wave], end = row_off[wave + 1];
    const char* htb = (const char*)ht;
    unsigned coff = (unsigned)(chunk << 3);
    float4 a0 = {0, 0, 0, 0}, a1 = {0, 0, 0, 0};
    for (int e = beg; e < end; e += 16) {
        int ei0 = e + eslot, ei1 = e + 8 + eslot;
        int2 d0 = ep[min(ei0, end - 1)];
        int2 d1 = ep[min(ei1, end - 1)];
        float w0 = (ei0 < end) ? __int_as_float(d0.y) : 0.0f;
        float w1 = (ei1 < end) ? __int_as_float(d1.y) : 0.0f;
        H4 r0, r1;
        r0.i2 = *(const int2*)(htb + (((unsigned)d0.x << 6) | coff));
        r1.i2 = *(const int2*)(htb + (((unsigned)d1.x << 6) | coff));
        a0.x = fmaf(__half2float(r0.h[0]), w0, a0.x);
        a0.y = fmaf(__half2float(r0.h[1]), w0, a0.y);
        a0.z = fmaf(__half2float(r0.h[2]), w0, a0.z);
        a0.w = fmaf(__half2float(r0.h[3]), w0, a0.w);
        a1.x = fmaf(__half2float(r1.h[0]), w1, a1.x);
        a1.y = fmaf(__half2float(r1.h[1]), w1, a1.y);
        a1.z = fmaf(__half2float(r1.h[2]), w1, a1.z);
        a1.w = fmaf(__half2float(r1.h[3]), w1, a1.w);
    }
    a0.x += a1.x; a0.y += a1.y; a0.z += a1.z; a0.w += a1.w;
    // butterfly-reduce across eslot (lane bits 3,4,5)
    #pragma unroll
    for (int s = 8; s <= 32; s <<= 1) {
        a0.x += __shfl_xor(a0.x, s, 64);
        a0.y += __shfl_xor(a0.y, s, 64);
        a0.z += __shfl_xor(a0.z, s, 64);
        a0.w += __shfl_xor(a0.w, s, 64);
    }
    float sc = indeg_inv[wave];
    float4 b = *(const float4*)(bias + chunk * 4);
    float4 w2 = *(const float4*)(W2 + chunk * 4);
    float t = tanhf(a0.x * sc + b.x) * w2.x
            + tanhf(a0.y * sc + b.y) * w2.y
            + tanhf(a0.z * sc + b.z) * w2.z
            + tanhf(a0.w * sc + b.w) * w2.w;
    t += __shfl_xor(t, 1, 64);
    t += __shfl_xor(t, 2, 64);
    t += __shfl_xor(t, 4, 64);
    if (lane == 0) ht2[wave] = t;
}

// C=1 final aggregation: 16 lanes per node (4 nodes/wave); coalesced edge reads
__global__ void agg1_kernel(const float* __restrict__ ht2, const int* __restrict__ row_off,
                            const int2* __restrict__ ep,
                            const float* __restrict__ indeg_inv, const float* __restrict__ bias,
                            float* __restrict__ out, int N) {
    int wave = (blockIdx.x * blockDim.x + threadIdx.x) >> 6;
    int lane = threadIdx.x & 63;
    int sub = lane >> 4;         // 0..3
    int slot = lane & 15;
    int node = wave * 4 + sub;
    if (node >= N) return;
    int beg = row_off[node], end = row_off[node + 1];
    float acc = 0.0f;
    for (int e = beg + slot; e < end; e += 16) {
        int2 t = ep[e];
        acc += ht2[t.x] * __int_as_float(t.y);
    }
    #pragma unroll
    for (int s = 1; s <= 8; s <<= 1) acc += __shfl_xor(acc, s, 64);  // within 16-lane group
    if (slot == 0) out[node] = acc * indeg_inv[node] + bias[0];
}

extern "C" void kernel_launch(void* const* d_in, const int* in_sizes, int n_in,
                              void* d_out, int out_size, void* d_ws, size_t ws_size,
                              hipStream_t stream) {
    const float* b_z = (const float*)d_in[0];
    const int*   src = (const int*)d_in[1];
    const int*   dst = (const int*)d_in[2];
    const float* ew  = (const float*)d_in[3];
    const float* W0 = (const float*)d_in[5];
    const float* b0 = (const float*)d_in[6];
    const float* W1 = (const float*)d_in[7];
    const float* b1 = (const float*)d_in[8];
    const float* W2 = (const float*)d_in[9];
    const float* b2 = (const float*)d_in[10];
    float* out = (float*)d_out;

    const int N = N_NODES;
    const int E = N_EDGES;

    // workspace layout (16B-aligned segments)
    char* p = (char*)d_ws;
    int*   row_off    = (int*)p;            p += (size_t)(N + 4) * 4;
    float* outdeg_inv = (float*)p;          p += (size_t)N * 4;
    float* indeg_inv  = (float*)p;          p += (size_t)N * 4;
    int*   histD      = (int*)p;            p += (size_t)PB * NB * 4;
    int*   histS      = (int*)p;            p += (size_t)PB * NB * 4;
    int*   offD       = (int*)p;            p += (size_t)PB * NB * 4;
    int*   offS       = (int*)p;            p += (size_t)PB * NB * 4;
    int*   coarseD    = (int*)p;            p += (size_t)(NB + 4) * 4;
    int*   coarseS    = (int*)p;            p += (size_t)(NB + 4) * 4;
    int2*  edge_perm  = (int2*)p;           p += (size_t)E * 8;
    float* bufA       = (float*)p;          p += (size_t)N * 64 * 4;
    float* bufB       = (float*)p;
    // aliases with disjoint lifetimes:
    int2*   partD = (int2*)bufA;    // dead after fineD; gemm0 then writes bufA (ht fp16, 13MB)
    int*    partS = (int*)bufB;     // dead after fineS; agg64_gemm then writes bufB (ht1 fp16)
    __half* ht    = (__half*)bufA;  // N x 64 fp16, written by gemm0, read by agg64_gemm
    __half* ht1   = (__half*)bufB;  // N x 32 fp16, written by agg64_gemm, read by agg32_dot
    float*  ht2   = bufA;           // N x 1 fp32, written by agg32_dot (ht dead by then)

    // ---- atomic-free CSR build (two-level counting sort) ----
    histA_kernel<<<PB, 256, 0, stream>>>(src, dst, histD, histS);
    scanB_kernel<<<1, 256, 0, stream>>>(histD, histS, offD, offS, coarseD, coarseS);
    partC_kernel<<<PB, 256, 0, stream>>>(src, dst, ew, offD, offS, partD, partS);
    fineS_kernel<<<NB, 1024, 0, stream>>>(partS, coarseS, outdeg_inv);
    fineD_kernel<<<NB, 1024, 0, stream>>>(partD, coarseD, outdeg_inv, edge_perm, row_off, indeg_inv);

    // ---- layer 0 transform: 128 -> 64, fp16 out ----
    gemm_tile_kernel<128, 64, 4><<<N / 64, 256, 0, stream>>>(b_z, W0, ht);

    // ---- layer 0 aggregation + tanh + fused layer-1 transform (64 -> 32), fp16 out ----
    agg64_gemm_kernel<<<N / 4, 256, 0, stream>>>(ht, row_off, edge_perm, indeg_inv, b0, W1, ht1, N);

    // ---- layer 1 aggregation + tanh + fused layer-2 transform (32 -> 1) ----
    agg32_dot_kernel<<<N / 4, 256, 0, stream>>>(ht1, row_off, edge_perm, indeg_inv, b1, W2, ht2, N);

    // ---- layer 2 aggregation -> out ----
    agg1_kernel<<<N / 16, 256, 0, stream>>>(ht2, row_off, edge_perm, indeg_inv, b2, out, N);
}